// Round 7
// baseline (336.628 us; speedup 1.0000x reference)
//
#include <hip/hip_runtime.h>
#include <hip/hip_cooperative_groups.h>
#include <math.h>

namespace cg = cooperative_groups;

#define LL 2048
#define HH 8
#define DD 64
#define SK 40
#define UU 40
#define SCALE 0.125f

__device__ __forceinline__ float dot4(float4 a, float4 b) {
  return a.x * b.x + a.y * b.y + a.z * b.z + a.w * b.w;
}

// layouts: Q/K/V [b][l][h][d]; out [b][h][l][d]
// ws: M 65536 | part 16384 | (unused) | Mtop 1280i | pm 10240 | pl 10240 | pO 655360

struct SmemM   { int sidx[4 * SK]; float wred[2][4][2][8]; };
struct SmemVP  { float sm[8][64]; };
struct SmemTK  { float sv[LL]; float wm[8]; int wi[8]; };
struct SmemFill{ float4 vm[16]; };
struct SmemAttn{ float4 Ks4[1024]; float Ps[8][256]; float4 Os4[4][2][4][16]; int gqi[8]; };
union SmemAll {
  SmemM m; SmemVP vp; SmemTK tk; SmemFill fl; SmemAttn at;
};

// ---------- phase 1a: sampled scores -> M (XCD-pinned gather) ----------
__device__ void phase_m(SmemAll& S, int v, int t,
                        const float* __restrict__ Q, const float* __restrict__ K,
                        const int* __restrict__ idxs, float* __restrict__ Mout)
{
  __syncthreads();                         // union/sidx reuse guard
  int xcd = v & 7, slot = v >> 3;          // slot 0..255
  int b = xcd >> 1;
  int l0 = ((xcd & 1) << 10) | (slot << 2);
  int w = t >> 6, lane = t & 63;
  int lpos = w >> 1, half = w & 1;
  int l = l0 + lpos;
  int h = (lane >> 2) & 7, dg = lane & 3, sp = lane >> 5;

  if (t < 4 * SK) S.m.sidx[t] = idxs[l0 * SK + t];

  const float4* Q4 = (const float4*)Q;
  int qb = (((b << 11) + l) << 7) + (h << 4) + dg;
  float4 q0 = Q4[qb], q1 = Q4[qb + 4], q2 = Q4[qb + 8], q3 = Q4[qb + 12];

  const float4* K4 = (const float4*)K;
  int kbb = (b << 18) + (h << 4) + dg;

  __syncthreads();

  const int* hidx = &S.m.sidx[lpos * SK + half * 20];
  float mx = -INFINITY, sum = 0.f;
#pragma unroll
  for (int pp = 0; pp < 10; pp += 2) {
    int i0 = hidx[pp * 2 + sp];
    int i1 = hidx[pp * 2 + 2 + sp];
    int o0 = kbb + (i0 << 7);
    int o1 = kbb + (i1 << 7);
    float4 a0 = K4[o0], a1 = K4[o0 + 4], a2 = K4[o0 + 8], a3 = K4[o0 + 12];
    float4 c0 = K4[o1], c1 = K4[o1 + 4], c2 = K4[o1 + 8], c3 = K4[o1 + 12];
    float p = dot4(q0, a0) + dot4(q1, a1) + dot4(q2, a2) + dot4(q3, a3);
    float r2 = dot4(q0, c0) + dot4(q1, c1) + dot4(q2, c2) + dot4(q3, c3);
    p += __shfl_xor(p, 1); p += __shfl_xor(p, 2);
    r2 += __shfl_xor(r2, 1); r2 += __shfl_xor(r2, 2);
    mx = fmaxf(mx, fmaxf(p, r2));
    sum += p + r2;
  }
  mx = fmaxf(mx, __shfl_xor(mx, 32));
  sum += __shfl_xor(sum, 32);
  if ((lane & 35) == 0) {                  // sp==0 && dg==0
    S.m.wred[0][lpos][half][h] = mx;
    S.m.wred[1][lpos][half][h] = sum;
  }
  __syncthreads();
  if (t < 32) {
    int lp = t >> 3, hh = t & 7;
    float M0 = fmaxf(S.m.wred[0][lp][0][hh], S.m.wred[0][lp][1][hh]);
    float S0 = S.m.wred[1][lp][0][hh] + S.m.wred[1][lp][1][hh];
    Mout[((b * HH + hh) << 11) + (l0 + lp)] = M0 - S0 * (1.0f / (float)LL);
  }
}

// ---------- phase 1b: partial V sums ----------
__device__ void phase_vpart(SmemAll& S, int blk, int t,
                            const float* __restrict__ V, float* __restrict__ part)
{
  __syncthreads();
  int bh = blk >> 3, c = blk & 7;
  int b = bh >> 3, h = bh & 7;
  int w = t >> 6, d = t & 63;
  int l0 = (c << 8) + (w << 5);
  int base = (b << 20) + (l0 << 9) + (h << 6) + d;
  float a0 = 0, a1 = 0, a2 = 0, a3 = 0;
#pragma unroll
  for (int j = 0; j < 32; j += 4) {
    a0 += V[base + ((j + 0) << 9)];
    a1 += V[base + ((j + 1) << 9)];
    a2 += V[base + ((j + 2) << 9)];
    a3 += V[base + ((j + 3) << 9)];
  }
  S.vp.sm[w][d] = a0 + a1 + a2 + a3;
  __syncthreads();
  if (t < 64) {
    float s = 0;
#pragma unroll
    for (int i = 0; i < 8; ++i) s += S.vp.sm[i][t];
    part[(blk << 6) + t] = s;
  }
}

// ---------- phase 2a: top-40 per (b,h), 8 waves ----------
__device__ void phase_topk(SmemAll& S, int bh, int t,
                           const float* __restrict__ Mv, int* __restrict__ Mtop)
{
  __syncthreads();
  int w = t >> 6, ln = t & 63;
  for (int i = t; i < LL; i += 512) S.tk.sv[i] = Mv[bh * LL + i];
  __syncthreads();
  for (int r = 0; r < UU; ++r) {
    float bv = -INFINITY; int bi = 0;
#pragma unroll
    for (int j = 0; j < 4; ++j) {
      int i = t + (j << 9);
      float vv = S.tk.sv[i];
      if (vv > bv) { bv = vv; bi = i; }
    }
#pragma unroll
    for (int off = 1; off < 64; off <<= 1) {
      float ov = __shfl_xor(bv, off);
      int oi = __shfl_xor(bi, off);
      if (ov > bv || (ov == bv && oi < bi)) { bv = ov; bi = oi; }
    }
    if (ln == 0) { S.tk.wm[w] = bv; S.tk.wi[w] = bi; }
    __syncthreads();
    if (t == 0) {
      float Bv = S.tk.wm[0]; int Bi = S.tk.wi[0];
#pragma unroll
      for (int k2 = 1; k2 < 8; ++k2)
        if (S.tk.wm[k2] > Bv || (S.tk.wm[k2] == Bv && S.tk.wi[k2] < Bi)) { Bv = S.tk.wm[k2]; Bi = S.tk.wi[k2]; }
      Mtop[bh * UU + r] = Bi;
      S.tk.sv[Bi] = -INFINITY;
    }
    __syncthreads();
  }
}

// ---------- phase 2b: Vmean + broadcast fill ----------
__device__ void phase_fill(SmemAll& S, int v, int t,
                           const float4* __restrict__ part4, float4* __restrict__ out4)
{
  __syncthreads();
  int bh = v >> 4;
  if (t < 16) {
    float4 s = {0, 0, 0, 0};
#pragma unroll
    for (int c = 0; c < 8; ++c) {
      float4 p = part4[((bh << 3) + c) * 16 + t];
      s.x += p.x; s.y += p.y; s.z += p.z; s.w += p.w;
    }
    const float inv = 1.0f / (float)LL;
    s.x *= inv; s.y *= inv; s.z *= inv; s.w *= inv;
    S.fl.vm[t] = s;
  }
  __syncthreads();
  int base = v << 11;
#pragma unroll
  for (int j = 0; j < 4; ++j) {
    int i = base + (j << 9) + t;
    out4[i] = S.fl.vm[i & 15];
  }
}

// ---------- phase 3: split-K attention partials (XCD-pinned) ----------
__device__ void phase_attn(SmemAll& S, int v, int t,
                           const float* __restrict__ Q, const float* __restrict__ K,
                           const float* __restrict__ V, const int* __restrict__ Mtop,
                           float* __restrict__ pm, float* __restrict__ pl,
                           float4* __restrict__ pO4)
{
  __syncthreads();
  int ch = v & 7;
  int slot = v >> 3;                  // 0..159
  int bh = slot / 5, rg = slot % 5;
  int b = bh >> 3, h = bh & 7;
  int w = t >> 6, ln = t & 63;
  int l0 = ch << 8;

  if (t < 8) S.at.gqi[t] = Mtop[bh * UU + rg * 8 + t];
  __syncthreads();

  float4 qv[16];
  {
    const float4* qrow = (const float4*)Q + (((b << 11) + S.at.gqi[w]) << 7) + (h << 4);
#pragma unroll
    for (int i = 0; i < 16; ++i) qv[i] = qrow[i];
  }

  const float4* K4 = (const float4*)K;
  int kbase = (((b << 11) + l0) << 7) + (h << 4);
  int col0 = t >> 4, d40 = t & 15;
  int sw0 = col0 * 16 + (d40 ^ (col0 & 7));
  float4 g0 = K4[kbase + col0 * 128 + d40];
  float4 g1 = K4[kbase + (col0 + 32) * 128 + d40];

  float sc[4];
#pragma unroll
  for (int st = 0; st < 4; ++st) {
    __syncthreads();
    S.at.Ks4[sw0] = g0;
    S.at.Ks4[sw0 + 512] = g1;
    float4 n0, n1;
    if (st < 3) {
      int lr = (st + 1) * 64;
      n0 = K4[kbase + (lr + col0) * 128 + d40];
      n1 = K4[kbase + (lr + col0 + 32) * 128 + d40];
    }
    __syncthreads();
    float s = 0.f;
#pragma unroll
    for (int d4 = 0; d4 < 16; ++d4) {
      float4 kv = S.at.Ks4[ln * 16 + (d4 ^ (ln & 7))];
      s += qv[d4].x * kv.x + qv[d4].y * kv.y + qv[d4].z * kv.z + qv[d4].w * kv.w;
    }
    sc[st] = s * SCALE;
    g0 = n0; g1 = n1;
  }

  float m = fmaxf(fmaxf(sc[0], sc[1]), fmaxf(sc[2], sc[3]));
#pragma unroll
  for (int off = 1; off < 64; off <<= 1) m = fmaxf(m, __shfl_xor(m, off));
  float lsum = 0.f;
#pragma unroll
  for (int st = 0; st < 4; ++st) {
    float p = __expf(sc[st] - m);
    S.at.Ps[w][st * 64 + ln] = p;
    lsum += p;
  }
#pragma unroll
  for (int off = 1; off < 64; off <<= 1) lsum += __shfl_xor(lsum, off);
  if (ln == 0) {
    int prow = bh * UU + rg * 8 + w;
    pm[prow * 8 + ch] = m;
    pl[prow * 8 + ch] = lsum;
  }
  __syncthreads();

  int rw = w >> 2, cq = w & 3;
  int cg2 = ln >> 4, d4 = ln & 15;
  float4 o0 = {0,0,0,0}, o1 = {0,0,0,0}, o2 = {0,0,0,0}, o3 = {0,0,0,0};
  int vb = (((b << 11) + l0 + cq * 64) << 7) + (h << 4);
  const float4* V4 = (const float4*)V;
#pragma unroll
  for (int i = 0; i < 16; ++i) {
    int c = i * 4 + cg2;
    float4 v4 = V4[vb + c * 128 + d4];
    float p0 = S.at.Ps[rw * 4 + 0][cq * 64 + c];
    float p1 = S.at.Ps[rw * 4 + 1][cq * 64 + c];
    float p2 = S.at.Ps[rw * 4 + 2][cq * 64 + c];
    float p3 = S.at.Ps[rw * 4 + 3][cq * 64 + c];
    o0.x += p0 * v4.x; o0.y += p0 * v4.y; o0.z += p0 * v4.z; o0.w += p0 * v4.w;
    o1.x += p1 * v4.x; o1.y += p1 * v4.y; o1.z += p1 * v4.z; o1.w += p1 * v4.w;
    o2.x += p2 * v4.x; o2.y += p2 * v4.y; o2.z += p2 * v4.z; o2.w += p2 * v4.w;
    o3.x += p3 * v4.x; o3.y += p3 * v4.y; o3.z += p3 * v4.z; o3.w += p3 * v4.w;
  }
#pragma unroll
  for (int off = 16; off <= 32; off <<= 1) {
    o0.x += __shfl_xor(o0.x, off); o0.y += __shfl_xor(o0.y, off);
    o0.z += __shfl_xor(o0.z, off); o0.w += __shfl_xor(o0.w, off);
    o1.x += __shfl_xor(o1.x, off); o1.y += __shfl_xor(o1.y, off);
    o1.z += __shfl_xor(o1.z, off); o1.w += __shfl_xor(o1.w, off);
    o2.x += __shfl_xor(o2.x, off); o2.y += __shfl_xor(o2.y, off);
    o2.z += __shfl_xor(o2.z, off); o2.w += __shfl_xor(o2.w, off);
    o3.x += __shfl_xor(o3.x, off); o3.y += __shfl_xor(o3.y, off);
    o3.z += __shfl_xor(o3.z, off); o3.w += __shfl_xor(o3.w, off);
  }
  if (cg2 == 0) {
    S.at.Os4[cq][rw][0][d4] = o0;
    S.at.Os4[cq][rw][1][d4] = o1;
    S.at.Os4[cq][rw][2][d4] = o2;
    S.at.Os4[cq][rw][3][d4] = o3;
  }
  __syncthreads();

  if (t < 128) {
    int r = t >> 4, dd = t & 15;
    float4 a  = S.at.Os4[0][r >> 2][r & 3][dd];
    float4 bq = S.at.Os4[1][r >> 2][r & 3][dd];
    float4 cc = S.at.Os4[2][r >> 2][r & 3][dd];
    float4 dq = S.at.Os4[3][r >> 2][r & 3][dd];
    float4 s;
    s.x = a.x + bq.x + cc.x + dq.x;
    s.y = a.y + bq.y + cc.y + dq.y;
    s.z = a.z + bq.z + cc.z + dq.z;
    s.w = a.w + bq.w + cc.w + dq.w;
    int prow = bh * UU + rg * 8 + r;
    pO4[(prow * 8 + ch) * 16 + dd] = s;
  }
}

// ---------- phase 4: merge chunk partials ----------
__device__ void phase_comb(int v, int t,
                           const float* __restrict__ pm, const float* __restrict__ pl,
                           const float* __restrict__ pO, const int* __restrict__ Mtop,
                           float* __restrict__ out)
{
  int row = v * 8 + (t >> 6);         // 0..1279
  int ln = t & 63;
  int bh = row / UU, r40 = row % UU;
  float mm[8];
#pragma unroll
  for (int c = 0; c < 8; ++c) mm[c] = pm[row * 8 + c];
  float ms = mm[0];
#pragma unroll
  for (int c = 1; c < 8; ++c) ms = fmaxf(ms, mm[c]);
  float wsum = 0.f, o = 0.f;
#pragma unroll
  for (int c = 0; c < 8; ++c) {
    float wc = __expf(mm[c] - ms);
    wsum += wc * pl[row * 8 + c];
    o += wc * pO[(row * 8 + c) * 64 + ln];
  }
  int gq = Mtop[bh * UU + r40];
  out[((bh * LL + gq) << 6) + ln] = o / wsum;
}

// ================ the single cooperative kernel (grid MUST be 256) ================
__global__ __launch_bounds__(512, 2) void k_mega(
    const float* __restrict__ Q, const float* __restrict__ K,
    const float* __restrict__ V, const int* __restrict__ idxs,
    float* __restrict__ M, float* __restrict__ part, int* __restrict__ Mtop,
    float* __restrict__ pm, float* __restrict__ pl, float* __restrict__ pO,
    float* __restrict__ out)
{
  __shared__ SmemAll S;
  cg::grid_group gg = cg::this_grid();
  int r = blockIdx.x, t = threadIdx.x;
  const int G = 256;

  // phase 1: sampled scores (2048 vblocks, 8 per block) + V partial sums (256, 1 per block)
  for (int v = r; v < 2304; v += G) {
    if (v < 2048) phase_m(S, v, t, Q, K, idxs, M);
    else          phase_vpart(S, v - 2048, t, V, part);
  }
  gg.sync();

  // phase 2: blocks 0..31 -> topk (exclusive); blocks 32..255 -> 512 fill vblocks
  if (r < 32) {
    phase_topk(S, r, t, M, Mtop);
  } else {
    for (int v = r - 32; v < 512; v += G - 32)
      phase_fill(S, v, t, (const float4*)part, (float4*)out);
  }
  gg.sync();

  // phase 3: split-K attention partials (1280 vblocks, 5 per block; ch = v&7 pinned)
  for (int v = r; v < 1280; v += G)
    phase_attn(S, v, t, Q, K, V, Mtop, pm, pl, (float4*)pO);
  gg.sync();

  // phase 4: merge (160 vblocks)
  for (int v = r; v < 160; v += G)
    phase_comb(v, t, pm, pl, pO, Mtop, out);
}

// ================ fallback wrappers (same phase code, 4 plain launches) ================
__global__ __launch_bounds__(512, 2) void k_f1(
    const float* __restrict__ Q, const float* __restrict__ K,
    const float* __restrict__ V, const int* __restrict__ idxs,
    float* __restrict__ M, float* __restrict__ part)
{
  __shared__ SmemAll S;
  int v = blockIdx.x, t = threadIdx.x;
  if (v < 2048) phase_m(S, v, t, Q, K, idxs, M);
  else          phase_vpart(S, v - 2048, t, V, part);
}
__global__ __launch_bounds__(512, 2) void k_f2(
    const float* __restrict__ M, int* __restrict__ Mtop,
    const float4* __restrict__ part4, float4* __restrict__ out4)
{
  __shared__ SmemAll S;
  int v = blockIdx.x, t = threadIdx.x;
  if (v < 32) phase_topk(S, v, t, M, Mtop);
  else        phase_fill(S, v - 32, t, part4, out4);
}
__global__ __launch_bounds__(512, 2) void k_f3(
    const float* __restrict__ Q, const float* __restrict__ K,
    const float* __restrict__ V, const int* __restrict__ Mtop,
    float* __restrict__ pm, float* __restrict__ pl, float4* __restrict__ pO4)
{
  __shared__ SmemAll S;
  phase_attn(S, blockIdx.x, threadIdx.x, Q, K, V, Mtop, pm, pl, pO4);
}
__global__ __launch_bounds__(512, 2) void k_f4(
    const float* __restrict__ pm, const float* __restrict__ pl,
    const float* __restrict__ pO, const int* __restrict__ Mtop,
    float* __restrict__ out)
{
  phase_comb(blockIdx.x, threadIdx.x, pm, pl, pO, Mtop, out);
}

extern "C" void kernel_launch(void* const* d_in, const int* in_sizes, int n_in,
                              void* d_out, int out_size, void* d_ws, size_t ws_size,
                              hipStream_t stream)
{
  (void)in_sizes; (void)n_in; (void)out_size; (void)ws_size;
  const float* Q = (const float*)d_in[0];
  const float* K = (const float*)d_in[1];
  const float* V = (const float*)d_in[2];
  const int* idxs = (const int*)d_in[3];
  float* out = (float*)d_out;

  float* wsf = (float*)d_ws;
  float* M     = wsf;                   // 65536
  float* part  = wsf + 65536;           // 16384
  int*   Mtop  = (int*)(wsf + 83968);   // 1280
  float* pm    = wsf + 85248;           // 10240
  float* pl    = wsf + 95488;           // 10240
  float* pO    = wsf + 105728;          // 655360

  void* args[] = { (void*)&Q, (void*)&K, (void*)&V, (void*)&idxs,
                   (void*)&M, (void*)&part, (void*)&Mtop,
                   (void*)&pm, (void*)&pl, (void*)&pO, (void*)&out };
  hipError_t e = hipLaunchCooperativeKernel((const void*)k_mega, dim3(256), dim3(512),
                                            args, 0, stream);
  if (e != hipSuccess) {
    (void)hipGetLastError();   // clear error state; run identical work as 4 plain launches
    k_f1<<<2304, 512, 0, stream>>>(Q, K, V, idxs, M, part);
    k_f2<<<544,  512, 0, stream>>>(M, Mtop, (const float4*)part, (float4*)out);
    k_f3<<<1280, 512, 0, stream>>>(Q, K, V, Mtop, pm, pl, (float4*)pO);
    k_f4<<<160,  512, 0, stream>>>(pm, pl, pO, Mtop, out);
  }
}

// Round 8
// 206.189 us; speedup vs baseline: 1.6326x; 1.6326x over previous
//
#include <hip/hip_runtime.h>
#include <math.h>

#define LL 2048
#define HH 8
#define DD 64
#define SK 40
#define UU 40
#define SCALE 0.125f

__device__ __forceinline__ float dot4(float4 a, float4 b) {
  return a.x * b.x + a.y * b.y + a.z * b.z + a.w * b.w;
}

// layouts: Q/K/V [b][l][h][d]; out [b][h][l][d]
// ws: M 65536 | part 16384 | (unused) | Mtop 1280i | pm 10240 | pl 10240 | pO 655360

// ================ Kernel A: sampled scores -> M  (+ fused V partial sums) ================
// k_m role (bx < 2048): XCD-pinned xcd=bx&7, b=xcd>>1 (per-XCD gather set = K[b] = 4MB = L2).
// Lane = sp*32 + h*4 + dg; 16 dims/lane via interleaved f4 slots {dg,dg+4,dg+8,dg+12}.
// Deep MLP: two register banks of 5 samples x 4 float4; ALL 40 loads issued before any
// consume (counted vmcnt overlaps 20 outstanding gathers with the dot-product phase).
// __launch_bounds__(512,2) permits ~200 VGPR so the banks live in registers, not a chain.
__global__ __launch_bounds__(512, 2) void k_A(
    const float* __restrict__ Q, const float* __restrict__ K,
    const float* __restrict__ V, const int* __restrict__ idxs,
    float* __restrict__ Mout, float* __restrict__ part)
{
  int bx = blockIdx.x;
  int t = threadIdx.x;

  if (bx < 2048) {
    // ---------------- k_m ----------------
    __shared__ int sidx[4 * SK];
    __shared__ float wred[2][4][2][8];   // [mx|sum][lpos][half][h]

    int xcd = bx & 7, slot = bx >> 3;    // slot 0..255
    int b = xcd >> 1;
    int l0 = ((xcd & 1) << 10) | (slot << 2);
    int w = t >> 6, lane = t & 63;
    int lpos = w >> 1, half = w & 1;
    int l = l0 + lpos;
    int h = (lane >> 2) & 7, dg = lane & 3, sp = lane >> 5;

    if (t < 4 * SK) sidx[t] = idxs[l0 * SK + t];

    const float4* Q4 = (const float4*)Q;
    int qb = (((b << 11) + l) << 7) + (h << 4) + dg;
    float4 q0 = Q4[qb], q1 = Q4[qb + 4], q2 = Q4[qb + 8], q3 = Q4[qb + 12];

    const float4* K4 = (const float4*)K;
    int kbb = (b << 18) + (h << 4) + dg;

    __syncthreads();

    const int* hx = &sidx[lpos * SK + half * 20];

    // -------- issue ALL 40 gather loads (banks A, B) before any consume --------
    float4 A[5][4], Bv[5][4];
    int oA[5], oB[5];
#pragma unroll
    for (int j = 0; j < 5; ++j) oA[j] = kbb + (hx[2 * j + sp] << 7);
#pragma unroll
    for (int j = 0; j < 5; ++j) {
      A[j][0] = K4[oA[j]];     A[j][1] = K4[oA[j] + 4];
      A[j][2] = K4[oA[j] + 8]; A[j][3] = K4[oA[j] + 12];
    }
#pragma unroll
    for (int j = 0; j < 5; ++j) oB[j] = kbb + (hx[10 + 2 * j + sp] << 7);
#pragma unroll
    for (int j = 0; j < 5; ++j) {
      Bv[j][0] = K4[oB[j]];     Bv[j][1] = K4[oB[j] + 4];
      Bv[j][2] = K4[oB[j] + 8]; Bv[j][3] = K4[oB[j] + 12];
    }

    float mx = -INFINITY, sum = 0.f;
#pragma unroll
    for (int j = 0; j < 5; ++j) {
      float p = dot4(q0, A[j][0]) + dot4(q1, A[j][1])
              + dot4(q2, A[j][2]) + dot4(q3, A[j][3]);
      p += __shfl_xor(p, 1);
      p += __shfl_xor(p, 2);
      mx = fmaxf(mx, p);
      sum += p;
    }
#pragma unroll
    for (int j = 0; j < 5; ++j) {
      float p = dot4(q0, Bv[j][0]) + dot4(q1, Bv[j][1])
              + dot4(q2, Bv[j][2]) + dot4(q3, Bv[j][3]);
      p += __shfl_xor(p, 1);
      p += __shfl_xor(p, 2);
      mx = fmaxf(mx, p);
      sum += p;
    }
    mx = fmaxf(mx, __shfl_xor(mx, 32));
    sum += __shfl_xor(sum, 32);
    if ((lane & 35) == 0) {              // sp==0 && dg==0
      wred[0][lpos][half][h] = mx;
      wred[1][lpos][half][h] = sum;
    }
    __syncthreads();
    if (t < 32) {
      int lp = t >> 3, hh = t & 7;
      float M0 = fmaxf(wred[0][lp][0][hh], wred[0][lp][1][hh]);
      float S0 = wred[1][lp][0][hh] + wred[1][lp][1][hh];
      Mout[((b * HH + hh) << 11) + (l0 + lp)] = M0 - S0 * (1.0f / (float)LL);
    }
  } else {
    // ---------------- vpart (512-thread): blk = (bh<<3)+chunk ----------------
    __shared__ float sm[8][64];
    int blk = bx - 2048;                 // 0..255
    int bh = blk >> 3, c = blk & 7;
    int b = bh >> 3, h = bh & 7;
    int w = t >> 6, d = t & 63;
    int l0 = (c << 8) + (w << 5);
    int base = (b << 20) + (l0 << 9) + (h << 6) + d;
    float a0 = 0, a1 = 0, a2 = 0, a3 = 0;
#pragma unroll
    for (int j = 0; j < 32; j += 4) {
      a0 += V[base + ((j + 0) << 9)];
      a1 += V[base + ((j + 1) << 9)];
      a2 += V[base + ((j + 2) << 9)];
      a3 += V[base + ((j + 3) << 9)];
    }
    sm[w][d] = a0 + a1 + a2 + a3;
    __syncthreads();
    if (t < 64) {
      float s = 0;
#pragma unroll
      for (int i = 0; i < 8; ++i) s += sm[i][t];
      part[(blk << 6) + t] = s;
    }
  }
}

// ================ Kernel B: top-40 per (b,h)  (+ fused Vmean broadcast fill) ================
__global__ __launch_bounds__(256) void k_B(
    const float* __restrict__ Mv, int* __restrict__ Mtop,
    const float4* __restrict__ part4, float4* __restrict__ out4)
{
  int bx = blockIdx.x;
  int t = threadIdx.x;

  if (bx < 32) {
    // ---------------- topk ----------------
    __shared__ float sv[LL];
    __shared__ float wm[4];
    __shared__ int wi[4];
    int bh = bx;
    int w = t >> 6, ln = t & 63;
    for (int i = t; i < LL; i += 256) sv[i] = Mv[bh * LL + i];
    __syncthreads();
    for (int r = 0; r < UU; ++r) {
      float bv = -INFINITY; int bi = 0;
#pragma unroll
      for (int j = 0; j < 8; ++j) {
        int i = t + (j << 8);
        float v = sv[i];
        if (v > bv) { bv = v; bi = i; }
      }
#pragma unroll
      for (int off = 1; off < 64; off <<= 1) {
        float ov = __shfl_xor(bv, off);
        int oi = __shfl_xor(bi, off);
        if (ov > bv || (ov == bv && oi < bi)) { bv = ov; bi = oi; }
      }
      if (ln == 0) { wm[w] = bv; wi[w] = bi; }
      __syncthreads();
      if (t == 0) {
        float Bv = wm[0]; int Bi = wi[0];
#pragma unroll
        for (int k = 1; k < 4; ++k)
          if (wm[k] > Bv || (wm[k] == Bv && wi[k] < Bi)) { Bv = wm[k]; Bi = wi[k]; }
        Mtop[bh * UU + r] = Bi;
        sv[Bi] = -INFINITY;
      }
      __syncthreads();
    }
  } else {
    // ---------------- Vmean + fill ----------------
    __shared__ float4 vm[16];
    int i = (bx - 32) * 256 + t;         // float4 index, 0..1048575
    int bh = i >> 15;
    if (t < 16) {
      int d4 = t;
      float4 s = {0, 0, 0, 0};
#pragma unroll
      for (int c = 0; c < 8; ++c) {
        float4 p = part4[((bh << 3) + c) * 16 + d4];
        s.x += p.x; s.y += p.y; s.z += p.z; s.w += p.w;
      }
      const float inv = 1.0f / (float)LL;
      s.x *= inv; s.y *= inv; s.z *= inv; s.w *= inv;
      vm[d4] = s;
    }
    __syncthreads();
    out4[i] = vm[i & 15];
  }
}

// ================ Kernel C: split-K attention partials ================
// XCD-pinned: ch = bx&7; per-XCD working set = 32bh * 128KB = 4MB = L2.
__global__ __launch_bounds__(512) void k_attn2(
    const float* __restrict__ Q, const float* __restrict__ K,
    const float* __restrict__ V, const int* __restrict__ Mtop,
    float* __restrict__ pm, float* __restrict__ pl, float4* __restrict__ pO4)
{
  __shared__ float4 Ks4[1024];        // swizzled: [col*16 + (d4^(col&7))]
  __shared__ float Ps[8][256];
  __shared__ float4 Os4[4][2][4][16]; // [cq][rw][r][d4]
  __shared__ int gqi[8];

  int bx = blockIdx.x;
  int ch = bx & 7;
  int slot = bx >> 3;                 // 0..159
  int bh = slot / 5, rg = slot % 5;
  int b = bh >> 3, h = bh & 7;
  int t = threadIdx.x;
  int w = t >> 6, ln = t & 63;
  int l0 = ch << 8;

  if (t < 8) gqi[t] = Mtop[bh * UU + rg * 8 + t];
  __syncthreads();

  float4 qv[16];
  {
    const float4* qrow = (const float4*)Q + (((b << 11) + gqi[w]) << 7) + (h << 4);
#pragma unroll
    for (int i = 0; i < 16; ++i) qv[i] = qrow[i];
  }

  const float4* K4 = (const float4*)K;
  int kbase = (((b << 11) + l0) << 7) + (h << 4);
  int col0 = t >> 4, d40 = t & 15;
  int sw0 = col0 * 16 + (d40 ^ (col0 & 7));
  float4 g0 = K4[kbase + col0 * 128 + d40];
  float4 g1 = K4[kbase + (col0 + 32) * 128 + d40];

  float sc[4];
#pragma unroll
  for (int st = 0; st < 4; ++st) {
    __syncthreads();
    Ks4[sw0] = g0;
    Ks4[sw0 + 512] = g1;
    float4 n0, n1;
    if (st < 3) {
      int lr = (st + 1) * 64;
      n0 = K4[kbase + (lr + col0) * 128 + d40];
      n1 = K4[kbase + (lr + col0 + 32) * 128 + d40];
    }
    __syncthreads();
    float s = 0.f;
#pragma unroll
    for (int d4 = 0; d4 < 16; ++d4) {
      float4 kv = Ks4[ln * 16 + (d4 ^ (ln & 7))];
      s += qv[d4].x * kv.x + qv[d4].y * kv.y + qv[d4].z * kv.z + qv[d4].w * kv.w;
    }
    sc[st] = s * SCALE;
    g0 = n0; g1 = n1;
  }

  float m = fmaxf(fmaxf(sc[0], sc[1]), fmaxf(sc[2], sc[3]));
#pragma unroll
  for (int off = 1; off < 64; off <<= 1) m = fmaxf(m, __shfl_xor(m, off));
  float lsum = 0.f;
#pragma unroll
  for (int st = 0; st < 4; ++st) {
    float p = __expf(sc[st] - m);
    Ps[w][st * 64 + ln] = p;
    lsum += p;
  }
#pragma unroll
  for (int off = 1; off < 64; off <<= 1) lsum += __shfl_xor(lsum, off);
  if (ln == 0) {
    int prow = bh * UU + rg * 8 + w;
    pm[prow * 8 + ch] = m;
    pl[prow * 8 + ch] = lsum;
  }
  __syncthreads();

  int rw = w >> 2, cq = w & 3;
  int cg = ln >> 4, d4 = ln & 15;
  float4 o0 = {0,0,0,0}, o1 = {0,0,0,0}, o2 = {0,0,0,0}, o3 = {0,0,0,0};
  int vb = (((b << 11) + l0 + cq * 64) << 7) + (h << 4);
  const float4* V4 = (const float4*)V;
#pragma unroll
  for (int i = 0; i < 16; ++i) {
    int c = i * 4 + cg;
    float4 v4 = V4[vb + c * 128 + d4];
    float p0 = Ps[rw * 4 + 0][cq * 64 + c];
    float p1 = Ps[rw * 4 + 1][cq * 64 + c];
    float p2 = Ps[rw * 4 + 2][cq * 64 + c];
    float p3 = Ps[rw * 4 + 3][cq * 64 + c];
    o0.x += p0 * v4.x; o0.y += p0 * v4.y; o0.z += p0 * v4.z; o0.w += p0 * v4.w;
    o1.x += p1 * v4.x; o1.y += p1 * v4.y; o1.z += p1 * v4.z; o1.w += p1 * v4.w;
    o2.x += p2 * v4.x; o2.y += p2 * v4.y; o2.z += p2 * v4.z; o2.w += p2 * v4.w;
    o3.x += p3 * v4.x; o3.y += p3 * v4.y; o3.z += p3 * v4.z; o3.w += p3 * v4.w;
  }
#pragma unroll
  for (int off = 16; off <= 32; off <<= 1) {
    o0.x += __shfl_xor(o0.x, off); o0.y += __shfl_xor(o0.y, off);
    o0.z += __shfl_xor(o0.z, off); o0.w += __shfl_xor(o0.w, off);
    o1.x += __shfl_xor(o1.x, off); o1.y += __shfl_xor(o1.y, off);
    o1.z += __shfl_xor(o1.z, off); o1.w += __shfl_xor(o1.w, off);
    o2.x += __shfl_xor(o2.x, off); o2.y += __shfl_xor(o2.y, off);
    o2.z += __shfl_xor(o2.z, off); o2.w += __shfl_xor(o2.w, off);
    o3.x += __shfl_xor(o3.x, off); o3.y += __shfl_xor(o3.y, off);
    o3.z += __shfl_xor(o3.z, off); o3.w += __shfl_xor(o3.w, off);
  }
  if (cg == 0) {
    Os4[cq][rw][0][d4] = o0;
    Os4[cq][rw][1][d4] = o1;
    Os4[cq][rw][2][d4] = o2;
    Os4[cq][rw][3][d4] = o3;
  }
  __syncthreads();

  if (t < 128) {
    int r = t >> 4, dd = t & 15;
    float4 a = Os4[0][r >> 2][r & 3][dd];
    float4 bq = Os4[1][r >> 2][r & 3][dd];
    float4 cc = Os4[2][r >> 2][r & 3][dd];
    float4 dq = Os4[3][r >> 2][r & 3][dd];
    float4 s;
    s.x = a.x + bq.x + cc.x + dq.x;
    s.y = a.y + bq.y + cc.y + dq.y;
    s.z = a.z + bq.z + cc.z + dq.z;
    s.w = a.w + bq.w + cc.w + dq.w;
    int prow = bh * UU + rg * 8 + r;
    pO4[(prow * 8 + ch) * 16 + dd] = s;
  }
}

// ================ Kernel D: merge chunk partials ================
__global__ __launch_bounds__(256) void k_comb(
    const float* __restrict__ pm, const float* __restrict__ pl,
    const float* __restrict__ pO, const int* __restrict__ Mtop,
    float* __restrict__ out)
{
  int row = blockIdx.x * 4 + (threadIdx.x >> 6);  // 0..1279
  int ln = threadIdx.x & 63;
  int bh = row / UU, r40 = row % UU;
  float mm[8];
#pragma unroll
  for (int c = 0; c < 8; ++c) mm[c] = pm[row * 8 + c];
  float ms = mm[0];
#pragma unroll
  for (int c = 1; c < 8; ++c) ms = fmaxf(ms, mm[c]);
  float wsum = 0.f, o = 0.f;
#pragma unroll
  for (int c = 0; c < 8; ++c) {
    float wc = __expf(mm[c] - ms);
    wsum += wc * pl[row * 8 + c];
    o += wc * pO[(row * 8 + c) * 64 + ln];
  }
  int gq = Mtop[bh * UU + r40];
  out[((bh * LL + gq) << 6) + ln] = o / wsum;
}

extern "C" void kernel_launch(void* const* d_in, const int* in_sizes, int n_in,
                              void* d_out, int out_size, void* d_ws, size_t ws_size,
                              hipStream_t stream)
{
  (void)in_sizes; (void)n_in; (void)out_size; (void)ws_size;
  const float* Q = (const float*)d_in[0];
  const float* K = (const float*)d_in[1];
  const float* V = (const float*)d_in[2];
  const int* idxs = (const int*)d_in[3];
  float* out = (float*)d_out;

  float* wsf = (float*)d_ws;
  float* M     = wsf;                   // 65536
  float* part  = wsf + 65536;           // 16384
  int*   Mtop  = (int*)(wsf + 83968);   // 1280
  float* pm    = wsf + 85248;           // 10240
  float* pl    = wsf + 95488;           // 10240
  float* pO    = wsf + 105728;          // 655360

  k_A    <<<2304, 512, 0, stream>>>(Q, K, V, idxs, M, part);
  k_B    <<<4128, 256, 0, stream>>>(M, Mtop, (const float4*)part, (float4*)out);
  k_attn2<<<1280, 512, 0, stream>>>(Q, K, V, Mtop, pm, pl, (float4*)pO);
  k_comb <<<320,  256, 0, stream>>>(pm, pl, pO, Mtop, out);
}